// Round 8
// baseline (2049.807 us; speedup 1.0000x reference)
//
#include <hip/hip_runtime.h>
#include <hip/hip_bf16.h>
#include <math.h>

// Problem constants
#define Bn   16
#define Dn   64
#define Tn   3000
#define Nn   (Bn*Tn)          // 48000
#define NCB  8
#define Kn   1024
#define KTB  128              // codes per block (k-chunk)
#define KSPL (Kn/KTB)         // 8 k-chunks
#define NTB  64               // n per block
#define NBLK (Nn/NTB)         // 750 (exact)
#define NTIL ((Nn + 255)/256) // 188 (for comb/qt grids)
#define PSTR 48128            // padded partial stride
#define EPSF 8e-3f            // candidate band (lo*lo err bound ~5e-4 -> need 2e-3; 4x margin)

// LDS layout (bytes)
#define SM_RH   0                      // bf16 [64n][64d] swizzled = 8192
#define SM_RL   8192                   // 8192
#define SM_EH   16384                  // bf16 [128k][64d] swizzled = 16384
#define SM_EL   32768                  // 16384
#define SM_RF   49152                  // float [64d][66n] = 16896 (exact r copy)
#define SM_SE2  66048                  // float[128] = 512
#define SM_SR2  66560                  // float[64] = 256
#define SM_SRP2 66816                  // float[4][64] = 1024
#define SM_WMIN 67840                  // float[4][64] = 1024
#define SM_CAND 68864                  // float2[4][64] = 2048
#define SM_TOT2 70912                  // -> 2 blocks/CU

// Workspace byte offsets
#define WS_RES  0                              // float[3072000] residual
#define WS_PVAL 12288000                       // float[KSPL*PSTR]
#define WS_PIDX (WS_PVAL + KSPL*PSTR*4)        // int[KSPL*PSTR]
#define WS_SE   (WS_PIDX + KSPL*PSTR*4)        // float[NCB*Kn]
#define WS_USED (WS_SE + NCB*Kn*4)             // float[NCB*Kn]
#define WS_LOSS (WS_USED + NCB*Kn*4)           // float[1] (+pad)

// Output element offsets (fp32 elements)
#define OUT_QT_OFF  0
#define OUT_IDX_OFF 3072000
#define OUT_SC_OFF  3456000

typedef __attribute__((ext_vector_type(4))) float f32x4;
typedef __attribute__((ext_vector_type(8))) short s16x8;
typedef __attribute__((ext_vector_type(4))) short s16x4;

__device__ __forceinline__ unsigned short f2bf(float x) {   // RNE bf16 bits
    unsigned int u = __float_as_uint(x);
    unsigned int r = (u + 0x7FFFu + ((u >> 16) & 1u)) >> 16;
    return (unsigned short)r;
}
__device__ __forceinline__ float bf2f(unsigned short h) {
    return __uint_as_float(((unsigned int)h) << 16);
}

// ---------- precompute ||e_k||^2 for all 8 codebooks ----------
__global__ void vq_se(const float* __restrict__ emb, float* __restrict__ se)
{
    int r = blockIdx.x * 256 + threadIdx.x;   // 0..8191
    if (r < NCB*Kn) {
        const float* p = emb + r*Dn;
        float a0=0.f, a1=0.f, a2=0.f, a3=0.f;
        #pragma unroll
        for (int d = 0; d < Dn; d += 4) {
            a0 = fmaf(p[d+0], p[d+0], a0);
            a1 = fmaf(p[d+1], p[d+1], a1);
            a2 = fmaf(p[d+2], p[d+2], a2);
            a3 = fmaf(p[d+3], p[d+3], a3);
        }
        se[r] = (a0+a1)+(a2+a3);
    }
}

// exact fp32 rescore: d2 = (sr - 2*dot) + se_k  (rare path)
// kg is the GLOBAL code index (kbase + kl); selds indexed by local kl.
__device__ __attribute__((noinline))
float vq_rescore(const float* rf, const float* lds_sr, const float* selds,
                 const float* __restrict__ emb, int n, int kl, int kg)
{
    const float4* ep = (const float4*)(emb + (size_t)kg*Dn);
    float q0=0.f,q1=0.f,q2=0.f,q3=0.f;
    #pragma unroll 4
    for (int m = 0; m < 16; ++m) {
        float4 e4 = ep[m];
        q0 = fmaf(rf[(4*m+0)*66 + n], e4.x, q0);
        q1 = fmaf(rf[(4*m+1)*66 + n], e4.y, q1);
        q2 = fmaf(rf[(4*m+2)*66 + n], e4.z, q2);
        q3 = fmaf(rf[(4*m+3)*66 + n], e4.w, q3);
    }
    float dot = (q0+q1)+(q2+q3);
    return (lds_sr[n] - 2.0f*dot) + selds[kl];
}

// ---------- MFMA distance filter + exact rescore + per-chunk argmin ----------
// grid (NBLK, KSPL), block 256 (4 waves). Scores S[128k][64n] via 3-pass bf16 split.
__global__ __launch_bounds__(256, 2)
void vq_dist(const float* __restrict__ res, const float* __restrict__ emb,
             const float* __restrict__ se,
             float* __restrict__ pval, int* __restrict__ pidx)
{
    __shared__ __align__(16) char smem[SM_TOT2];
    float*  rf     = (float*)(smem + SM_RF);
    float*  selds  = (float*)(smem + SM_SE2);
    float*  lds_sr = (float*)(smem + SM_SR2);
    float*  srpart = (float*)(smem + SM_SRP2);
    float*  wmin   = (float*)(smem + SM_WMIN);
    float2* cand   = (float2*)(smem + SM_CAND);

    const int tid = threadIdx.x;
    const int n0 = blockIdx.x * NTB;
    const int kbase = blockIdx.y * KTB;

    // ---- stage R: fp32 copy [d][66], bf16 hi/lo swizzled [n][d], sr partials ----
    {
        const int nl = tid & 63;
        const int dg = tid >> 6;             // 4 d-groups of 16
        const int n = n0 + nl;
        const int b = n / Tn, t = n % Tn;
        const float* gp = res + b*(Dn*Tn) + t;
        float v[16];
        #pragma unroll
        for (int j = 0; j < 16; ++j) v[j] = gp[(dg*16 + j)*Tn];
        float a0=0.f,a1=0.f,a2=0.f,a3=0.f;
        #pragma unroll
        for (int j = 0; j < 16; j += 4) {
            a0 = fmaf(v[j+0], v[j+0], a0);
            a1 = fmaf(v[j+1], v[j+1], a1);
            a2 = fmaf(v[j+2], v[j+2], a2);
            a3 = fmaf(v[j+3], v[j+3], a3);
        }
        srpart[dg*64 + nl] = (a0+a1)+(a2+a3);
        unsigned short hi[16], lo[16];
        #pragma unroll
        for (int j = 0; j < 16; ++j) {
            rf[(dg*16 + j)*66 + nl] = v[j];
            hi[j] = f2bf(v[j]);
            lo[j] = f2bf(v[j] - bf2f(hi[j]));
        }
        s16x8 ph0, ph1, pl0, pl1;
        #pragma unroll
        for (int j = 0; j < 8; ++j) {
            ph0[j] = (short)hi[j];   ph1[j] = (short)hi[j+8];
            pl0[j] = (short)lo[j];   pl1[j] = (short)lo[j+8];
        }
        const int s0 = dg*2, s1 = dg*2 + 1, nx = nl & 7;
        *(s16x8*)(smem + SM_RH + nl*128 + ((s0 ^ nx) << 4)) = ph0;
        *(s16x8*)(smem + SM_RH + nl*128 + ((s1 ^ nx) << 4)) = ph1;
        *(s16x8*)(smem + SM_RL + nl*128 + ((s0 ^ nx) << 4)) = pl0;
        *(s16x8*)(smem + SM_RL + nl*128 + ((s1 ^ nx) << 4)) = pl1;
    }
    // ---- stage E: bf16 hi/lo swizzled [k][d] ----
    {
        const float4* src = (const float4*)(emb + (size_t)kbase*Dn);
        #pragma unroll
        for (int jj = 0; jj < 8; ++jj) {
            int f = tid + jj*256;            // 0..2047
            int k = f >> 4;
            int d0 = (f & 15) * 4;
            int s = d0 >> 3;
            int ho = (d0 & 4) ? 8 : 0;
            float4 v = src[f];
            unsigned short h0=f2bf(v.x), h1=f2bf(v.y), h2=f2bf(v.z), h3=f2bf(v.w);
            s16x4 hh; hh[0]=(short)h0; hh[1]=(short)h1; hh[2]=(short)h2; hh[3]=(short)h3;
            s16x4 ll;
            ll[0]=(short)f2bf(v.x - bf2f(h0)); ll[1]=(short)f2bf(v.y - bf2f(h1));
            ll[2]=(short)f2bf(v.z - bf2f(h2)); ll[3]=(short)f2bf(v.w - bf2f(h3));
            size_t base = (size_t)k*128 + ((s ^ (k & 7)) << 4) + ho;
            *(s16x4*)(smem + SM_EH + base) = hh;
            *(s16x4*)(smem + SM_EL + base) = ll;
        }
        if (tid < KTB) selds[tid] = se[kbase + tid];
    }
    __syncthreads();
    if (tid < 64)
        lds_sr[tid] = (srpart[tid] + srpart[64+tid]) + (srpart[128+tid] + srpart[192+tid]);

    // ---- MFMA: acc[i][j] = E[w*32+i*16..][:] . R[j*16..][:]  (3-pass split) ----
    const int lane = tid & 63, w = tid >> 6;
    const int lrow = lane & 15, lhi = lane >> 4;
    f32x4 acc[2][4] = {};
    #pragma unroll
    for (int ks = 0; ks < 2; ++ks) {
        const int s = ks*4 + lhi;
        const int erow = w*32 + lrow;
        const size_t eoff = (size_t)erow*128 + ((s ^ (erow & 7)) << 4);
        const size_t roff = (size_t)lrow*128 + ((s ^ (lrow & 7)) << 4);
        s16x8 ah0 = *(const s16x8*)(smem + SM_EH + eoff);
        s16x8 ah1 = *(const s16x8*)(smem + SM_EH + eoff + 2048);
        s16x8 al0 = *(const s16x8*)(smem + SM_EL + eoff);
        s16x8 al1 = *(const s16x8*)(smem + SM_EL + eoff + 2048);
        s16x8 bh[4], bl[4];
        #pragma unroll
        for (int j = 0; j < 4; ++j) {
            bh[j] = *(const s16x8*)(smem + SM_RH + roff + j*2048);
            bl[j] = *(const s16x8*)(smem + SM_RL + roff + j*2048);
        }
        #pragma unroll
        for (int j = 0; j < 4; ++j) {
            acc[0][j] = __builtin_amdgcn_mfma_f32_16x16x32_bf16(ah0, bh[j], acc[0][j], 0, 0, 0);
            acc[1][j] = __builtin_amdgcn_mfma_f32_16x16x32_bf16(ah1, bh[j], acc[1][j], 0, 0, 0);
            acc[0][j] = __builtin_amdgcn_mfma_f32_16x16x32_bf16(ah0, bl[j], acc[0][j], 0, 0, 0);
            acc[1][j] = __builtin_amdgcn_mfma_f32_16x16x32_bf16(ah1, bl[j], acc[1][j], 0, 0, 0);
            acc[0][j] = __builtin_amdgcn_mfma_f32_16x16x32_bf16(al0, bh[j], acc[0][j], 0, 0, 0);
            acc[1][j] = __builtin_amdgcn_mfma_f32_16x16x32_bf16(al1, bh[j], acc[1][j], 0, 0, 0);
        }
    }

    // ---- epilogue: approx min -> candidate band -> exact rescore -> chunk argmin ----
    float se8[8];
    #pragma unroll
    for (int i = 0; i < 2; ++i)
        #pragma unroll
        for (int rg = 0; rg < 4; ++rg)
            se8[i*4+rg] = selds[w*32 + i*16 + lhi*4 + rg];

    float amin[4] = { INFINITY, INFINITY, INFINITY, INFINITY };
    #pragma unroll
    for (int j = 0; j < 4; ++j)
        #pragma unroll
        for (int i = 0; i < 2; ++i)
            #pragma unroll
            for (int rg = 0; rg < 4; ++rg) {
                float c = se8[i*4+rg] - 2.0f*acc[i][j][rg];
                amin[j] = fminf(amin[j], c);
            }
    #pragma unroll
    for (int j = 0; j < 4; ++j) {
        amin[j] = fminf(amin[j], __shfl_xor(amin[j], 16, 64));
        amin[j] = fminf(amin[j], __shfl_xor(amin[j], 32, 64));
    }
    if (lhi == 0)
        #pragma unroll
        for (int j = 0; j < 4; ++j) wmin[w*64 + j*16 + lrow] = amin[j];
    __syncthreads();

    float gmin[4];
    #pragma unroll
    for (int j = 0; j < 4; ++j) {
        int n = j*16 + lrow;
        gmin[j] = fminf(fminf(wmin[n], wmin[64+n]), fminf(wmin[128+n], wmin[192+n]));
    }

    float bval[4] = { INFINITY, INFINITY, INFINITY, INFINITY };
    int   bk_[4]  = { 0x7FFFFFFF, 0x7FFFFFFF, 0x7FFFFFFF, 0x7FFFFFFF };
    #pragma unroll
    for (int i = 0; i < 2; ++i)
        #pragma unroll
        for (int rg = 0; rg < 4; ++rg) {
            const int kl = w*32 + i*16 + lhi*4 + rg;
            #pragma unroll
            for (int j = 0; j < 4; ++j) {
                float c = se8[i*4+rg] - 2.0f*acc[i][j][rg];
                if (c <= gmin[j] + EPSF) {
                    int n = j*16 + lrow;
                    int kg = kbase + kl;
                    float d2e = vq_rescore(rf, lds_sr, selds, emb, n, kl, kg);
                    if (d2e < bval[j] || (d2e == bval[j] && kg < bk_[j])) {
                        bval[j] = d2e; bk_[j] = kg;
                    }
                }
            }
        }
    #pragma unroll
    for (int j = 0; j < 4; ++j) {
        #pragma unroll
        for (int mask = 16; mask <= 32; mask <<= 1) {
            float ov = __shfl_xor(bval[j], mask, 64);
            int   ok = __shfl_xor(bk_[j],  mask, 64);
            if (ov < bval[j] || (ov == bval[j] && ok < bk_[j])) { bval[j] = ov; bk_[j] = ok; }
        }
    }
    if (lhi == 0)
        #pragma unroll
        for (int j = 0; j < 4; ++j) {
            float2 v; v.x = bval[j]; v.y = __int_as_float(bk_[j]);
            cand[w*64 + j*16 + lrow] = v;
        }
    __syncthreads();
    if (tid < 64) {
        float best = INFINITY; int bk = 0x7FFFFFFF;
        #pragma unroll
        for (int x = 0; x < 4; ++x) {          // w ascending = k ascending
            float2 v = cand[x*64 + tid];
            int ok = __float_as_int(v.y);
            if (v.x < best || (v.x == best && ok < bk)) { best = v.x; bk = ok; }
        }
        pval[blockIdx.y*PSTR + n0 + tid] = best;
        pidx[blockIdx.y*PSTR + n0 + tid] = bk;
    }
}

// ---------- combine partials + residual update + loss/util ----------
__global__ void vq_comb(float* __restrict__ res, const float* __restrict__ emb,
                        const float* __restrict__ pval, const int* __restrict__ pidx,
                        float* __restrict__ out_idx,             // + stage*Nn (fp32)
                        float* __restrict__ used,                // + stage*Kn
                        float* __restrict__ loss_acc)
{
    __shared__ float red[256];
    const int tid = threadIdx.x;
    const int n = blockIdx.x * 256 + tid;
    float lsum = 0.f;
    if (n < Nn) {
        float best = INFINITY; int bk = 0;
        #pragma unroll
        for (int c = 0; c < KSPL; ++c) {          // ascending chunks: first-occurrence
            float v = pval[c*PSTR + n];
            int   k = pidx[c*PSTR + n];
            if (v < best) { best = v; bk = k; }
        }
        bk &= (Kn - 1);                           // provably no-op OOB guard
        out_idx[n] = (float)bk;
        used[bk] = 1.0f;
        const int b = n / Tn, t = n % Tn;
        float* rp = res + b*(Dn*Tn) + t;
        const float* ep = emb + bk*Dn;
        #pragma unroll
        for (int d = 0; d < Dn; ++d) {
            float rv = rp[d*Tn];
            float q  = ep[d];
            float diff = rv - q;                  // loss uses raw q
            lsum = fmaf(diff, diff, lsum);
            float qst = rv + (q - rv);            // straight-through, fp32-faithful
            rp[d*Tn] = rv - qst;
        }
    }
    red[tid] = lsum;
    __syncthreads();
    for (int s2 = 128; s2 > 0; s2 >>= 1) {
        if (tid < s2) red[tid] += red[tid + s2];
        __syncthreads();
    }
    if (tid == 0) atomicAdd(loss_acc, red[0]);
}

// ---------- quantized_total = x - residual_final (fp32 out) ----------
__global__ void vq_qt(const float* __restrict__ x, const float* __restrict__ res,
                      float* __restrict__ out)
{
    int j = blockIdx.x * 256 + threadIdx.x;   // float4 units: 768000
    if (j < (Nn*Dn)/4) {
        float4 xv = ((const float4*)x)[j];
        float4 rv = ((const float4*)res)[j];
        float4 o;
        o.x = xv.x - rv.x;
        o.y = xv.y - rv.y;
        o.z = xv.z - rv.z;
        o.w = xv.w - rv.w;
        ((float4*)out)[j] = o;
    }
}

// ---------- scalars: (commit+codebook)/NCB and utilization (fp32 out) ----------
__global__ void vq_scalars(const float* __restrict__ used, const float* __restrict__ loss_acc,
                           float* __restrict__ out)
{
    __shared__ float red[256];
    float s = 0.f;
    for (int j = threadIdx.x; j < NCB*Kn; j += 256) s += used[j];
    red[threadIdx.x] = s;
    __syncthreads();
    for (int st = 128; st > 0; st >>= 1) {
        if (threadIdx.x < st) red[threadIdx.x] += red[threadIdx.x + st];
        __syncthreads();
    }
    if (threadIdx.x == 0) {
        float sumsq = loss_acc[0];
        float total_loss = 2.0f * sumsq / (float)(Nn*Dn);  // sum over stages of commit+codebook
        out[OUT_SC_OFF + 0] = total_loss / (float)NCB;
        out[OUT_SC_OFF + 1] = red[0] / (float)(NCB*Kn);
    }
}

extern "C" void kernel_launch(void* const* d_in, const int* in_sizes, int n_in,
                              void* d_out, int out_size, void* d_ws, size_t ws_size,
                              hipStream_t stream)
{
    const float* x      = (const float*)d_in[0];
    const float* embeds = (const float*)d_in[1];
    float* out = (float*)d_out;
    char* ws = (char*)d_ws;

    float* res  = (float*)(ws + WS_RES);
    float* pval = (float*)(ws + WS_PVAL);
    int*   pidx = (int*)  (ws + WS_PIDX);
    float* se   = (float*)(ws + WS_SE);
    float* used = (float*)(ws + WS_USED);
    float* loss = (float*)(ws + WS_LOSS);

    // init: residual = x; used/loss = 0
    hipMemcpyAsync(res, x, (size_t)Nn*Dn*sizeof(float), hipMemcpyDeviceToDevice, stream);
    hipMemsetAsync(used, 0, (size_t)NCB*Kn*sizeof(float) + 16, stream);

    vq_se<<<(NCB*Kn + 255)/256, 256, 0, stream>>>(embeds, se);

    for (int s = 0; s < NCB; ++s) {
        const float* emb_s = embeds + (size_t)s*Kn*Dn;
        vq_dist<<<dim3(NBLK, KSPL), 256, 0, stream>>>(res, emb_s, se + s*Kn, pval, pidx);
        vq_comb<<<NTIL, 256, 0, stream>>>(res, emb_s, pval, pidx,
                                          out + OUT_IDX_OFF + s*Nn,
                                          used + s*Kn, loss);
    }

    vq_qt<<<((Nn*Dn)/4 + 255)/256, 256, 0, stream>>>(x, res, out + OUT_QT_OFF);
    vq_scalars<<<1, 256, 0, stream>>>(used, loss, out);
}

// Round 9
// 759.465 us; speedup vs baseline: 2.6990x; 2.6990x over previous
//
#include <hip/hip_runtime.h>
#include <hip/hip_bf16.h>
#include <math.h>

// Problem constants
#define Bn   16
#define Dn   64
#define Tn   3000
#define Nn   (Bn*Tn)          // 48000
#define NCB  8
#define Kn   1024
#define KTB  128              // codes per k-chunk (LDS staged)
#define NCHK (Kn/KTB)         // 8 chunks, looped inside the block
#define NTB  64               // n per block
#define NBLK (Nn/NTB)         // 750 (exact)
#define EPSF 8e-3f            // candidate band (3-pass split err ~5e-5; huge margin)
#define QMAX 1024

// LDS layout (bytes)
#define SM_RH   0                      // bf16 [64n][64d] swizzled = 8192
#define SM_RL   8192                   // 8192
#define SM_EH   16384                  // bf16 [128k][64d] swizzled = 16384
#define SM_EL   32768                  // 16384
#define SM_RF   49152                  // float [64d][66n] = 16896 (exact r copy)
#define SM_SE2  66048                  // float[128] = 512
#define SM_SR2  66560                  // float[64] = 256
#define SM_SRP2 66816                  // float[4][64] = 1024 (dead after prologue; reused as red[256])
#define SM_WMIN 67840                  // float[4][64] = 1024 (dead after loop; reused as bkL[64])
#define SM_BEST 68864                  // u64[64] = 512
#define SM_QCNT 69376                  // int (+12 pad)
#define SM_QUE  69392                  // u32[QMAX] = 4096
#define SM_TOT2 73488                  // -> 2 blocks/CU

// Workspace byte offsets
#define WS_RES  0                              // float[3072000] residual
#define WS_SE   12288000                       // float[NCB*Kn]
#define WS_USED (WS_SE + NCB*Kn*4)             // float[NCB*Kn]
#define WS_LOSS (WS_USED + NCB*Kn*4)           // float[1] (+pad)

// Output element offsets (fp32 elements)
#define OUT_QT_OFF  0
#define OUT_IDX_OFF 3072000
#define OUT_SC_OFF  3456000

typedef __attribute__((ext_vector_type(4))) float f32x4;
typedef __attribute__((ext_vector_type(8))) short s16x8;
typedef __attribute__((ext_vector_type(4))) short s16x4;

__device__ __forceinline__ unsigned short f2bf(float x) {   // RNE bf16 bits
    unsigned int u = __float_as_uint(x);
    unsigned int r = (u + 0x7FFFu + ((u >> 16) & 1u)) >> 16;
    return (unsigned short)r;
}
__device__ __forceinline__ float bf2f(unsigned short h) {
    return __uint_as_float(((unsigned int)h) << 16);
}

// ---------- precompute ||e_k||^2 for all 8 codebooks ----------
__global__ void vq_se(const float* __restrict__ emb, float* __restrict__ se)
{
    int r = blockIdx.x * 256 + threadIdx.x;   // 0..8191
    if (r < NCB*Kn) {
        const float* p = emb + r*Dn;
        float a0=0.f, a1=0.f, a2=0.f, a3=0.f;
        #pragma unroll
        for (int d = 0; d < Dn; d += 4) {
            a0 = fmaf(p[d+0], p[d+0], a0);
            a1 = fmaf(p[d+1], p[d+1], a1);
            a2 = fmaf(p[d+2], p[d+2], a2);
            a3 = fmaf(p[d+3], p[d+3], a3);
        }
        se[r] = (a0+a1)+(a2+a3);
    }
}

// exact fp32 rescore: d2 = (sr - 2*dot) + se_k  (identical chain to R8, verified)
__device__ __forceinline__
float vq_rescore(const float* rf, const float* lds_sr, const float* selds,
                 const float* __restrict__ emb, int n, int kl, int kg)
{
    const float4* ep = (const float4*)(emb + (size_t)kg*Dn);
    float q0=0.f,q1=0.f,q2=0.f,q3=0.f;
    #pragma unroll 4
    for (int m = 0; m < 16; ++m) {
        float4 e4 = ep[m];
        q0 = fmaf(rf[(4*m+0)*66 + n], e4.x, q0);
        q1 = fmaf(rf[(4*m+1)*66 + n], e4.y, q1);
        q2 = fmaf(rf[(4*m+2)*66 + n], e4.z, q2);
        q3 = fmaf(rf[(4*m+3)*66 + n], e4.w, q3);
    }
    float dot = (q0+q1)+(q2+q3);
    return (lds_sr[n] - 2.0f*dot) + selds[kl];
}

// ---------- fused per-stage: MFMA filter + queue rescore + argmin + update ----------
// grid NBLK, block 256 (4 waves). Block owns 64 n rows; loops all 8 k-chunks.
__global__ __launch_bounds__(256, 2)
void vq_stage_fused(const float* __restrict__ rin, float* __restrict__ res,
                    const float* __restrict__ emb, const float* __restrict__ se,
                    float* __restrict__ out_idx,             // + stage*Nn (fp32)
                    float* __restrict__ used,                // + stage*Kn
                    float* __restrict__ loss_acc)
{
    __shared__ __align__(16) char smem[SM_TOT2];
    float*  rf     = (float*)(smem + SM_RF);
    float*  selds  = (float*)(smem + SM_SE2);
    float*  lds_sr = (float*)(smem + SM_SR2);
    float*  srpart = (float*)(smem + SM_SRP2);
    float*  wmin   = (float*)(smem + SM_WMIN);
    unsigned long long* best64 = (unsigned long long*)(smem + SM_BEST);
    int*    qcnt   = (int*)(smem + SM_QCNT);
    unsigned int* que = (unsigned int*)(smem + SM_QUE);

    const int tid = threadIdx.x;
    const int n0 = blockIdx.x * NTB;
    const int lane = tid & 63, w = tid >> 6;
    const int lrow = lane & 15, lhi = lane >> 4;

    // ---- prologue: stage R (fp32 rf copy + bf16 hi/lo swizzled) + sr partials ----
    {
        const int nl = tid & 63;
        const int dg = tid >> 6;             // 4 d-groups of 16
        const int n = n0 + nl;
        const int b = n / Tn, t = n % Tn;
        const float* gp = rin + b*(Dn*Tn) + t;
        float v[16];
        #pragma unroll
        for (int j = 0; j < 16; ++j) v[j] = gp[(dg*16 + j)*Tn];
        float a0=0.f,a1=0.f,a2=0.f,a3=0.f;
        #pragma unroll
        for (int j = 0; j < 16; j += 4) {
            a0 = fmaf(v[j+0], v[j+0], a0);
            a1 = fmaf(v[j+1], v[j+1], a1);
            a2 = fmaf(v[j+2], v[j+2], a2);
            a3 = fmaf(v[j+3], v[j+3], a3);
        }
        srpart[dg*64 + nl] = (a0+a1)+(a2+a3);
        unsigned short hi[16], lo[16];
        #pragma unroll
        for (int j = 0; j < 16; ++j) {
            rf[(dg*16 + j)*66 + nl] = v[j];
            hi[j] = f2bf(v[j]);
            lo[j] = f2bf(v[j] - bf2f(hi[j]));
        }
        s16x8 ph0, ph1, pl0, pl1;
        #pragma unroll
        for (int j = 0; j < 8; ++j) {
            ph0[j] = (short)hi[j];   ph1[j] = (short)hi[j+8];
            pl0[j] = (short)lo[j];   pl1[j] = (short)lo[j+8];
        }
        const int s0 = dg*2, s1 = dg*2 + 1, nx = nl & 7;
        *(s16x8*)(smem + SM_RH + nl*128 + ((s0 ^ nx) << 4)) = ph0;
        *(s16x8*)(smem + SM_RH + nl*128 + ((s1 ^ nx) << 4)) = ph1;
        *(s16x8*)(smem + SM_RL + nl*128 + ((s0 ^ nx) << 4)) = pl0;
        *(s16x8*)(smem + SM_RL + nl*128 + ((s1 ^ nx) << 4)) = pl1;
    }
    if (tid < 64) best64[tid] = ~0ULL;
    if (tid == 0) *qcnt = 0;
    __syncthreads();
    if (tid < 64)
        lds_sr[tid] = (srpart[tid] + srpart[64+tid]) + (srpart[128+tid] + srpart[192+tid]);

    // ---- k-chunk loop ----
    for (int c = 0; c < NCHK; ++c) {
        const int kbase = c * KTB;
        // stage E chunk: bf16 hi/lo swizzled [k][d]
        {
            const float4* src = (const float4*)(emb + (size_t)kbase*Dn);
            #pragma unroll
            for (int jj = 0; jj < 8; ++jj) {
                int f = tid + jj*256;            // 0..2047
                int k = f >> 4;
                int d0 = (f & 15) * 4;
                int s = d0 >> 3;
                int ho = (d0 & 4) ? 8 : 0;
                float4 v = src[f];
                unsigned short h0=f2bf(v.x), h1=f2bf(v.y), h2=f2bf(v.z), h3=f2bf(v.w);
                s16x4 hh; hh[0]=(short)h0; hh[1]=(short)h1; hh[2]=(short)h2; hh[3]=(short)h3;
                s16x4 ll;
                ll[0]=(short)f2bf(v.x - bf2f(h0)); ll[1]=(short)f2bf(v.y - bf2f(h1));
                ll[2]=(short)f2bf(v.z - bf2f(h2)); ll[3]=(short)f2bf(v.w - bf2f(h3));
                size_t base = (size_t)k*128 + ((s ^ (k & 7)) << 4) + ho;
                *(s16x4*)(smem + SM_EH + base) = hh;
                *(s16x4*)(smem + SM_EL + base) = ll;
            }
            if (tid < KTB) selds[tid] = se[kbase + tid];
        }
        __syncthreads();

        // MFMA: acc[i][j] = E[w*32+i*16..][:] . R[j*16..][:]  (3-pass split)
        f32x4 acc[2][4] = {};
        #pragma unroll
        for (int ks = 0; ks < 2; ++ks) {
            const int s = ks*4 + lhi;
            const int erow = w*32 + lrow;
            const size_t eoff = (size_t)erow*128 + ((s ^ (erow & 7)) << 4);
            const size_t roff = (size_t)lrow*128 + ((s ^ (lrow & 7)) << 4);
            s16x8 ah0 = *(const s16x8*)(smem + SM_EH + eoff);
            s16x8 ah1 = *(const s16x8*)(smem + SM_EH + eoff + 2048);
            s16x8 al0 = *(const s16x8*)(smem + SM_EL + eoff);
            s16x8 al1 = *(const s16x8*)(smem + SM_EL + eoff + 2048);
            s16x8 bh[4], bl[4];
            #pragma unroll
            for (int j = 0; j < 4; ++j) {
                bh[j] = *(const s16x8*)(smem + SM_RH + roff + j*2048);
                bl[j] = *(const s16x8*)(smem + SM_RL + roff + j*2048);
            }
            #pragma unroll
            for (int j = 0; j < 4; ++j) {
                acc[0][j] = __builtin_amdgcn_mfma_f32_16x16x32_bf16(ah0, bh[j], acc[0][j], 0, 0, 0);
                acc[1][j] = __builtin_amdgcn_mfma_f32_16x16x32_bf16(ah1, bh[j], acc[1][j], 0, 0, 0);
                acc[0][j] = __builtin_amdgcn_mfma_f32_16x16x32_bf16(ah0, bl[j], acc[0][j], 0, 0, 0);
                acc[1][j] = __builtin_amdgcn_mfma_f32_16x16x32_bf16(ah1, bl[j], acc[1][j], 0, 0, 0);
                acc[0][j] = __builtin_amdgcn_mfma_f32_16x16x32_bf16(al0, bh[j], acc[0][j], 0, 0, 0);
                acc[1][j] = __builtin_amdgcn_mfma_f32_16x16x32_bf16(al1, bh[j], acc[1][j], 0, 0, 0);
            }
        }

        // approx chunk-min per n
        float se8[8];
        #pragma unroll
        for (int i = 0; i < 2; ++i)
            #pragma unroll
            for (int rg = 0; rg < 4; ++rg)
                se8[i*4+rg] = selds[w*32 + i*16 + lhi*4 + rg];

        float amin[4] = { INFINITY, INFINITY, INFINITY, INFINITY };
        #pragma unroll
        for (int j = 0; j < 4; ++j)
            #pragma unroll
            for (int i = 0; i < 2; ++i)
                #pragma unroll
                for (int rg = 0; rg < 4; ++rg) {
                    float cv = se8[i*4+rg] - 2.0f*acc[i][j][rg];
                    amin[j] = fminf(amin[j], cv);
                }
        #pragma unroll
        for (int j = 0; j < 4; ++j) {
            amin[j] = fminf(amin[j], __shfl_xor(amin[j], 16, 64));
            amin[j] = fminf(amin[j], __shfl_xor(amin[j], 32, 64));
        }
        if (lhi == 0)
            #pragma unroll
            for (int j = 0; j < 4; ++j) wmin[w*64 + j*16 + lrow] = amin[j];
        __syncthreads();

        float gmin[4];
        #pragma unroll
        for (int j = 0; j < 4; ++j) {
            int n = j*16 + lrow;
            gmin[j] = fminf(fminf(wmin[n], wmin[64+n]), fminf(wmin[128+n], wmin[192+n]));
        }

        // queue candidates (cheap push under divergence)
        #pragma unroll
        for (int i = 0; i < 2; ++i)
            #pragma unroll
            for (int rg = 0; rg < 4; ++rg) {
                const int kl = w*32 + i*16 + lhi*4 + rg;
                #pragma unroll
                for (int j = 0; j < 4; ++j) {
                    float cv = se8[i*4+rg] - 2.0f*acc[i][j][rg];
                    if (cv <= gmin[j] + EPSF) {
                        int nl = j*16 + lrow;
                        int slot = atomicAdd(qcnt, 1);
                        if (slot < QMAX) {
                            que[slot] = ((unsigned)nl << 7) | (unsigned)kl;
                        } else {   // overflow fallback (never in practice)
                            int kg = kbase + kl;
                            float d2e = vq_rescore(rf, lds_sr, selds, emb, nl, kl, kg);
                            unsigned long long pk =
                                ((unsigned long long)__float_as_uint(d2e) << 32) | (unsigned)kg;
                            atomicMin(&best64[nl], pk);
                        }
                    }
                }
            }
        __syncthreads();

        // parallel rescore of queued candidates
        const int cnt = min(*qcnt, QMAX);
        for (int e = tid; e < cnt; e += 256) {
            unsigned ent = que[e];
            int nl = (int)(ent >> 7);
            int kl = (int)(ent & 127);
            int kg = kbase + kl;
            float d2e = vq_rescore(rf, lds_sr, selds, emb, nl, kl, kg);
            unsigned long long pk =
                ((unsigned long long)__float_as_uint(d2e) << 32) | (unsigned)kg;
            atomicMin(&best64[nl], pk);
        }
        __syncthreads();
        if (tid == 0) *qcnt = 0;
        // (barrier at next chunk's post-stage covers qcnt reset visibility)
    }
    __syncthreads();

    // ---- finalize: write idx/used; residual update + loss ----
    int* bkL = (int*)(smem + SM_WMIN);        // wmin dead
    if (tid < 64) {
        int bk = (int)(best64[tid] & 0xFFFFFFFFull) & (Kn - 1);
        bkL[tid] = bk;
        out_idx[n0 + tid] = (float)bk;
        used[bk] = 1.0f;
    }
    __syncthreads();

    float lsum = 0.f;
    {
        const int nl = tid & 63;
        const int dg = tid >> 6;
        const int n = n0 + nl;
        const int b = n / Tn, t = n % Tn;
        float* rp = res + b*(Dn*Tn) + t;
        const float* ep = emb + (size_t)bkL[nl]*Dn;
        #pragma unroll
        for (int j = 0; j < 16; ++j) {
            int d = dg*16 + j;
            float rv = rf[d*66 + nl];
            float q  = ep[d];
            float diff = rv - q;                  // loss uses raw q
            lsum = fmaf(diff, diff, lsum);
            float qst = rv + (q - rv);            // straight-through, fp32-faithful
            rp[d*Tn] = rv - qst;
        }
    }
    float* red = (float*)(smem + SM_SRP2);    // srpart dead
    red[tid] = lsum;
    __syncthreads();
    for (int s2 = 128; s2 > 0; s2 >>= 1) {
        if (tid < s2) red[tid] += red[tid + s2];
        __syncthreads();
    }
    if (tid == 0) atomicAdd(loss_acc, red[0]);
}

// ---------- quantized_total = x - residual_final (fp32 out) ----------
__global__ void vq_qt(const float* __restrict__ x, const float* __restrict__ res,
                      float* __restrict__ out)
{
    int j = blockIdx.x * 256 + threadIdx.x;   // float4 units: 768000
    if (j < (Nn*Dn)/4) {
        float4 xv = ((const float4*)x)[j];
        float4 rv = ((const float4*)res)[j];
        float4 o;
        o.x = xv.x - rv.x;
        o.y = xv.y - rv.y;
        o.z = xv.z - rv.z;
        o.w = xv.w - rv.w;
        ((float4*)out)[j] = o;
    }
}

// ---------- scalars: (commit+codebook)/NCB and utilization (fp32 out) ----------
__global__ void vq_scalars(const float* __restrict__ used, const float* __restrict__ loss_acc,
                           float* __restrict__ out)
{
    __shared__ float red[256];
    float s = 0.f;
    for (int j = threadIdx.x; j < NCB*Kn; j += 256) s += used[j];
    red[threadIdx.x] = s;
    __syncthreads();
    for (int st = 128; st > 0; st >>= 1) {
        if (threadIdx.x < st) red[threadIdx.x] += red[threadIdx.x + st];
        __syncthreads();
    }
    if (threadIdx.x == 0) {
        float sumsq = loss_acc[0];
        float total_loss = 2.0f * sumsq / (float)(Nn*Dn);  // sum over stages of commit+codebook
        out[OUT_SC_OFF + 0] = total_loss / (float)NCB;
        out[OUT_SC_OFF + 1] = red[0] / (float)(NCB*Kn);
    }
}

extern "C" void kernel_launch(void* const* d_in, const int* in_sizes, int n_in,
                              void* d_out, int out_size, void* d_ws, size_t ws_size,
                              hipStream_t stream)
{
    const float* x      = (const float*)d_in[0];
    const float* embeds = (const float*)d_in[1];
    float* out = (float*)d_out;
    char* ws = (char*)d_ws;

    float* res  = (float*)(ws + WS_RES);
    float* se   = (float*)(ws + WS_SE);
    float* used = (float*)(ws + WS_USED);
    float* loss = (float*)(ws + WS_LOSS);

    hipMemsetAsync(used, 0, (size_t)NCB*Kn*sizeof(float) + 16, stream);

    vq_se<<<(NCB*Kn + 255)/256, 256, 0, stream>>>(embeds, se);

    for (int s = 0; s < NCB; ++s) {
        const float* emb_s = embeds + (size_t)s*Kn*Dn;
        const float* rin = (s == 0) ? x : res;   // stage 0 reads x directly
        vq_stage_fused<<<NBLK, 256, 0, stream>>>(rin, res, emb_s, se + s*Kn,
                                                 out + OUT_IDX_OFF + s*Nn,
                                                 used + s*Kn, loss);
    }

    vq_qt<<<((Nn*Dn)/4 + 255)/256, 256, 0, stream>>>(x, res, out + OUT_QT_OFF);
    vq_scalars<<<1, 256, 0, stream>>>(used, loss, out);
}

// Round 10
// 597.122 us; speedup vs baseline: 3.4328x; 1.2719x over previous
//
#include <hip/hip_runtime.h>
#include <hip/hip_bf16.h>
#include <math.h>

// Problem constants
#define Bn   16
#define Dn   64
#define Tn   3000
#define Nn   (Bn*Tn)          // 48000
#define NCB  8
#define Kn   1024
#define KTB  64               // codes per k-chunk (LDS staged)
#define NCHK (Kn/KTB)         // 16 chunks, looped inside the block
#define NTB  64               // n per block
#define NBLK (Nn/NTB)         // 750 (exact) <= 768 = 256CU x 3 blocks
#define EPSF 8e-3f            // candidate band (3-pass split err ~5e-5; huge margin)
#define QMAX 256

// LDS layout (bytes), total 52512 -> 3 blocks/CU
#define SM_RH   0                      // bf16 [64n][64d] swizzled = 8192
#define SM_RL   8192                   // 8192
#define SM_EH   16384                  // bf16 [64k][64d] swizzled = 8192
#define SM_EL   24576                  // 8192
#define SM_RF   32768                  // float [64d][64n] = 16384 (exact r copy)
#define SM_SE   49152                  // float[2][64] = 512 (parity selds)
#define SM_SR   49664                  // float[64] = 256
#define SM_BEST 49920                  // u64[64] = 512
#define SM_QCNT 50432                  // int[2] (+pad) = 32
#define SM_QUE  50464                  // u32[2][256] = 2048
#define SM_TOT  52512
// aliases: srpart[256]f (prologue) and red[256]f (finalize) live on SM_QUE;
//          bkL[64]i (finalize) lives on SM_SE.

// Workspace byte offsets
#define WS_RES  0                              // float[3072000] residual
#define WS_EHI  12288000                       // u8[8cb][16chk][8192] pre-swizzled bf16 hi
#define WS_ELO  13336576                       // same, lo
#define WS_SE   14385152                       // float[NCB*Kn]
#define WS_USED 14417920                       // float[NCB*Kn]
#define WS_LOSS 14450688                       // float[1] (+pad)

// Output element offsets (fp32 elements)
#define OUT_QT_OFF  0
#define OUT_IDX_OFF 3072000
#define OUT_SC_OFF  3456000

typedef __attribute__((ext_vector_type(4))) float f32x4;
typedef __attribute__((ext_vector_type(8))) short s16x8;

__device__ __forceinline__ unsigned short f2bf(float x) {   // RNE bf16 bits
    unsigned int u = __float_as_uint(x);
    unsigned int r = (u + 0x7FFFu + ((u >> 16) & 1u)) >> 16;
    return (unsigned short)r;
}
__device__ __forceinline__ float bf2f(unsigned short h) {
    return __uint_as_float(((unsigned int)h) << 16);
}

// ---------- precompute ||e_k||^2 for all 8 codebooks ----------
__global__ void vq_se(const float* __restrict__ emb, float* __restrict__ se)
{
    int r = blockIdx.x * 256 + threadIdx.x;   // 0..8191
    if (r < NCB*Kn) {
        const float* p = emb + r*Dn;
        float a0=0.f, a1=0.f, a2=0.f, a3=0.f;
        #pragma unroll
        for (int d = 0; d < Dn; d += 4) {
            a0 = fmaf(p[d+0], p[d+0], a0);
            a1 = fmaf(p[d+1], p[d+1], a1);
            a2 = fmaf(p[d+2], p[d+2], a2);
            a3 = fmaf(p[d+3], p[d+3], a3);
        }
        se[r] = (a0+a1)+(a2+a3);
    }
}

// ---------- precompute bf16 hi/lo split of all codebooks, pre-swizzled ----------
// One thread per (code, 8-dim slice): 8192*8 = 65536 threads.
__global__ void vq_ebf(const float* __restrict__ emb, char* __restrict__ ehi,
                       char* __restrict__ elo)
{
    int idx = blockIdx.x * 256 + threadIdx.x;   // < 65536
    int r = idx >> 3;                            // cb*1024 + k
    int s = idx & 7;                             // dim slice
    const float* p = emb + (size_t)r*Dn + s*8;
    s16x8 hh, ll;
    #pragma unroll
    for (int j = 0; j < 8; ++j) {
        float v = p[j];
        unsigned short h = f2bf(v);
        hh[j] = (short)h;
        ll[j] = (short)f2bf(v - bf2f(h));
    }
    int cb = r >> 10, kk = r & 1023, c = kk >> 6, kl = kk & 63;
    size_t off = (size_t)cb*131072 + (size_t)c*8192 + kl*128 + ((s ^ (kl & 7)) << 4);
    *(s16x8*)(ehi + off) = hh;
    *(s16x8*)(elo + off) = ll;
}

// exact fp32 rescore: d2 = (sr - 2*dot) + se_k  (identical chain since R8, verified)
__device__ __forceinline__
float vq_rescore(const float* rf, const float* lds_sr, const float* selds,
                 const float* __restrict__ emb, int n, int kl, int kg)
{
    const float4* ep = (const float4*)(emb + (size_t)kg*Dn);
    float q0=0.f,q1=0.f,q2=0.f,q3=0.f;
    #pragma unroll 4
    for (int m = 0; m < 16; ++m) {
        float4 e4 = ep[m];
        q0 = fmaf(rf[(4*m+0)*64 + n], e4.x, q0);
        q1 = fmaf(rf[(4*m+1)*64 + n], e4.y, q1);
        q2 = fmaf(rf[(4*m+2)*64 + n], e4.z, q2);
        q3 = fmaf(rf[(4*m+3)*64 + n], e4.w, q3);
    }
    float dot = (q0+q1)+(q2+q3);
    return (lds_sr[n] - 2.0f*dot) + selds[kl];
}

// ---------- fused per-stage: MFMA filter + queue rescore + argmin + update ----------
// grid NBLK, block 256 (4 waves). Wave w owns n-rows [w*16, w*16+16); chunk = 64 codes.
__global__ __launch_bounds__(256, 3)
void vq_stage_fused(const float* __restrict__ rin, float* __restrict__ res,
                    const float* __restrict__ emb,
                    const char* __restrict__ ehib, const char* __restrict__ elob,
                    const float* __restrict__ se,
                    float* __restrict__ out_idx,             // + stage*Nn (fp32)
                    float* __restrict__ used,                // + stage*Kn
                    float* __restrict__ loss_acc)
{
    __shared__ __align__(16) char smem[SM_TOT];
    float*  rf     = (float*)(smem + SM_RF);
    float*  seld2  = (float*)(smem + SM_SE);     // [2][64] parity
    float*  lds_sr = (float*)(smem + SM_SR);
    unsigned long long* best64 = (unsigned long long*)(smem + SM_BEST);
    int*    qcnt   = (int*)(smem + SM_QCNT);     // [2]
    unsigned int* que = (unsigned int*)(smem + SM_QUE);   // [2][256]
    float*  srpart = (float*)(smem + SM_QUE);    // alias (prologue only)

    const int tid = threadIdx.x;
    const int n0 = blockIdx.x * NTB;
    const int lane = tid & 63, w = tid >> 6;
    const int lrow = lane & 15, lhi = lane >> 4;
    const float4* hsrc = (const float4*)ehib;
    const float4* lsrc = (const float4*)elob;

    // ---- prologue: stage R (fp32 rf copy + bf16 hi/lo swizzled) + sr partials ----
    {
        const int nl = tid & 63;
        const int dg = tid >> 6;             // 4 d-groups of 16
        const int n = n0 + nl;
        const int b = n / Tn, t = n % Tn;
        const float* gp = rin + b*(Dn*Tn) + t;
        float v[16];
        #pragma unroll
        for (int j = 0; j < 16; ++j) v[j] = gp[(dg*16 + j)*Tn];
        float a0=0.f,a1=0.f,a2=0.f,a3=0.f;
        #pragma unroll
        for (int j = 0; j < 16; j += 4) {
            a0 = fmaf(v[j+0], v[j+0], a0);
            a1 = fmaf(v[j+1], v[j+1], a1);
            a2 = fmaf(v[j+2], v[j+2], a2);
            a3 = fmaf(v[j+3], v[j+3], a3);
        }
        srpart[dg*64 + nl] = (a0+a1)+(a2+a3);
        unsigned short hi[16], lo[16];
        #pragma unroll
        for (int j = 0; j < 16; ++j) {
            rf[(dg*16 + j)*64 + nl] = v[j];
            hi[j] = f2bf(v[j]);
            lo[j] = f2bf(v[j] - bf2f(hi[j]));
        }
        s16x8 ph0, ph1, pl0, pl1;
        #pragma unroll
        for (int j = 0; j < 8; ++j) {
            ph0[j] = (short)hi[j];   ph1[j] = (short)hi[j+8];
            pl0[j] = (short)lo[j];   pl1[j] = (short)lo[j+8];
        }
        const int s0 = dg*2, s1 = dg*2 + 1, nx = nl & 7;
        *(s16x8*)(smem + SM_RH + nl*128 + ((s0 ^ nx) << 4)) = ph0;
        *(s16x8*)(smem + SM_RH + nl*128 + ((s1 ^ nx) << 4)) = ph1;
        *(s16x8*)(smem + SM_RL + nl*128 + ((s0 ^ nx) << 4)) = pl0;
        *(s16x8*)(smem + SM_RL + nl*128 + ((s1 ^ nx) << 4)) = pl1;
    }
    if (tid < 64) best64[tid] = ~0ULL;
    if (tid < 2) qcnt[tid] = 0;
    __syncthreads();                               // bar0: srpart ready
    if (tid < 64)
        lds_sr[tid] = (srpart[tid] + srpart[64+tid]) + (srpart[128+tid] + srpart[192+tid]);
    // stage E chunk 0 (linear copy of pre-swizzled data)
    ((float4*)(smem + SM_EH))[tid] = hsrc[tid];
    ((float4*)(smem + SM_EH))[tid+256] = hsrc[tid+256];
    ((float4*)(smem + SM_EL))[tid] = lsrc[tid];
    ((float4*)(smem + SM_EL))[tid+256] = lsrc[tid+256];
    if (tid < 64) seld2[tid] = se[tid];
    __syncthreads();                               // bar1: E0+lds_sr ready, srpart dead

    // ---- k-chunk loop ----
    for (int c = 0; c < NCHK; ++c) {
        const int p = c & 1;
        const float* selds = seld2 + p*64;

        // MFMA: acc[i] = S[k = i*16 + krow][n = w*16 + ncol]  (3-pass split)
        f32x4 acc[4] = {};
        #pragma unroll
        for (int ks = 0; ks < 2; ++ks) {
            const int s = ks*4 + lhi;
            const int swz = ((s ^ (lrow & 7)) << 4);
            const size_t roff = (size_t)(w*16 + lrow)*128 + swz;
            const size_t eoff = (size_t)lrow*128 + swz;
            s16x8 bh = *(const s16x8*)(smem + SM_RH + roff);
            s16x8 bl = *(const s16x8*)(smem + SM_RL + roff);
            #pragma unroll
            for (int i = 0; i < 4; ++i) {
                s16x8 ah = *(const s16x8*)(smem + SM_EH + eoff + i*2048);
                s16x8 al = *(const s16x8*)(smem + SM_EL + eoff + i*2048);
                acc[i] = __builtin_amdgcn_mfma_f32_16x16x32_bf16(ah, bh, acc[i], 0, 0, 0);
                acc[i] = __builtin_amdgcn_mfma_f32_16x16x32_bf16(ah, bl, acc[i], 0, 0, 0);
                acc[i] = __builtin_amdgcn_mfma_f32_16x16x32_bf16(al, bh, acc[i], 0, 0, 0);
            }
        }

        // wave-local approx min over this chunk's 64 codes for my n
        float cv[4][4];
        float m = INFINITY;
        #pragma unroll
        for (int i = 0; i < 4; ++i)
            #pragma unroll
            for (int rg = 0; rg < 4; ++rg) {
                float c2 = selds[i*16 + lhi*4 + rg] - 2.0f*acc[i][rg];
                cv[i][rg] = c2;
                m = fminf(m, c2);
            }
        m = fminf(m, __shfl_xor(m, 16, 64));
        m = fminf(m, __shfl_xor(m, 32, 64));
        const float thr = m + EPSF;
        const int nlocal = w*16 + lrow;

        // queue candidates (cheap push)
        #pragma unroll
        for (int i = 0; i < 4; ++i)
            #pragma unroll
            for (int rg = 0; rg < 4; ++rg) {
                if (cv[i][rg] <= thr) {
                    int kl = i*16 + lhi*4 + rg;
                    int slot = atomicAdd(&qcnt[p], 1);
                    if (slot < QMAX) {
                        que[p*QMAX + slot] = ((unsigned)nlocal << 7) | (unsigned)kl;
                    } else {   // overflow fallback (never in practice)
                        int kg = c*KTB + kl;
                        float d2e = vq_rescore(rf, lds_sr, selds, emb, nlocal, kl, kg);
                        unsigned long long pk =
                            ((unsigned long long)__float_as_uint(d2e) << 32) | (unsigned)kg;
                        atomicMin(&best64[nlocal], pk);
                    }
                }
            }
        __syncthreads();        // pushes done, E(c) consumed

        const int cnt = min(qcnt[p], QMAX);
        const bool more = (c + 1 < NCHK);
        // issue next-chunk loads early (hide HBM/L2 latency under rescore)
        float4 h0, h1, l0, l1;
        if (more) {
            int base = (c+1) * 512;
            h0 = hsrc[base + tid]; h1 = hsrc[base + 256 + tid];
            l0 = lsrc[base + tid]; l1 = lsrc[base + 256 + tid];
        }
        // parallel rescore of queued candidates
        for (int e = tid; e < cnt; e += 256) {
            unsigned ent = que[p*QMAX + e];
            int nl = (int)(ent >> 7);
            int kl = (int)(ent & 127);
            int kg = c*KTB + kl;
            float d2e = vq_rescore(rf, lds_sr, selds, emb, nl, kl, kg);
            unsigned long long pk =
                ((unsigned long long)__float_as_uint(d2e) << 32) | (unsigned)kg;
            atomicMin(&best64[nl], pk);
        }
        if (tid == 0) qcnt[p^1] = 0;    // next parity (consumed two chunks ago)
        if (more) {
            ((float4*)(smem + SM_EH))[tid] = h0;
            ((float4*)(smem + SM_EH))[tid+256] = h1;
            ((float4*)(smem + SM_EL))[tid] = l0;
            ((float4*)(smem + SM_EL))[tid+256] = l1;
            if (tid < 64) seld2[(p^1)*64 + tid] = se[(c+1)*KTB + tid];
        }
        __syncthreads();        // E(c+1)/selds ready; rescore done
    }

    // ---- finalize: write idx/used; residual update + loss ----
    int* bkL = (int*)(smem + SM_SE);          // selds dead
    if (tid < 64) {
        int bk = (int)(best64[tid] & 0xFFFFFFFFull) & (Kn - 1);
        bkL[tid] = bk;
        out_idx[n0 + tid] = (float)bk;
        used[bk] = 1.0f;
    }
    __syncthreads();

    float lsum = 0.f;
    {
        const int nl = tid & 63;
        const int dg = tid >> 6;
        const int n = n0 + nl;
        const int b = n / Tn, t = n % Tn;
        float* rp = res + b*(Dn*Tn) + t;
        const float* ep = emb + (size_t)bkL[nl]*Dn;
        #pragma unroll
        for (int j = 0; j < 16; ++j) {
            int d = dg*16 + j;
            float rv = rf[d*64 + nl];
            float q  = ep[d];
            float diff = rv - q;                  // loss uses raw q
            lsum = fmaf(diff, diff, lsum);
            float qst = rv + (q - rv);            // straight-through, fp32-faithful
            rp[d*Tn] = rv - qst;
        }
    }
    float* red = (float*)(smem + SM_QUE);     // queue dead
    red[tid] = lsum;
    __syncthreads();
    for (int s2 = 128; s2 > 0; s2 >>= 1) {
        if (tid < s2) red[tid] += red[tid + s2];
        __syncthreads();
    }
    if (tid == 0) atomicAdd(loss_acc, red[0]);
}

// ---------- quantized_total = x - residual_final (fp32 out) ----------
__global__ void vq_qt(const float* __restrict__ x, const float* __restrict__ res,
                      float* __restrict__ out)
{
    int j = blockIdx.x * 256 + threadIdx.x;   // float4 units: 768000
    if (j < (Nn*Dn)/4) {
        float4 xv = ((const float4*)x)[j];
        float4 rv = ((const float4*)res)[j];
        float4 o;
        o.x = xv.x - rv.x;
        o.y = xv.y - rv.y;
        o.z = xv.z - rv.z;
        o.w = xv.w - rv.w;
        ((float4*)out)[j] = o;
    }
}

// ---------- scalars: (commit+codebook)/NCB and utilization (fp32 out) ----------
__global__ void vq_scalars(const float* __restrict__ used, const float* __restrict__ loss_acc,
                           float* __restrict__ out)
{
    __shared__ float red[256];
    float s = 0.f;
    for (int j = threadIdx.x; j < NCB*Kn; j += 256) s += used[j];
    red[threadIdx.x] = s;
    __syncthreads();
    for (int st = 128; st > 0; st >>= 1) {
        if (threadIdx.x < st) red[threadIdx.x] += red[threadIdx.x + st];
        __syncthreads();
    }
    if (threadIdx.x == 0) {
        float sumsq = loss_acc[0];
        float total_loss = 2.0f * sumsq / (float)(Nn*Dn);  // sum over stages of commit+codebook
        out[OUT_SC_OFF + 0] = total_loss / (float)NCB;
        out[OUT_SC_OFF + 1] = red[0] / (float)(NCB*Kn);
    }
}

extern "C" void kernel_launch(void* const* d_in, const int* in_sizes, int n_in,
                              void* d_out, int out_size, void* d_ws, size_t ws_size,
                              hipStream_t stream)
{
    const float* x      = (const float*)d_in[0];
    const float* embeds = (const float*)d_in[1];
    float* out = (float*)d_out;
    char* ws = (char*)d_ws;

    float* res  = (float*)(ws + WS_RES);
    char*  ehi  = ws + WS_EHI;
    char*  elo  = ws + WS_ELO;
    float* se   = (float*)(ws + WS_SE);
    float* used = (float*)(ws + WS_USED);
    float* loss = (float*)(ws + WS_LOSS);

    hipMemsetAsync(used, 0, (size_t)NCB*Kn*sizeof(float) + 16, stream);

    vq_se<<<(NCB*Kn + 255)/256, 256, 0, stream>>>(embeds, se);
    vq_ebf<<<256, 256, 0, stream>>>(embeds, ehi, elo);

    for (int s = 0; s < NCB; ++s) {
        const float* emb_s = embeds + (size_t)s*Kn*Dn;
        const float* rin = (s == 0) ? x : res;   // stage 0 reads x directly
        vq_stage_fused<<<NBLK, 256, 0, stream>>>(rin, res, emb_s,
                                                 ehi + (size_t)s*131072,
                                                 elo + (size_t)s*131072,
                                                 se + s*Kn,
                                                 out + OUT_IDX_OFF + s*Nn,
                                                 used + s*Kn, loss);
    }

    vq_qt<<<((Nn*Dn)/4 + 255)/256, 256, 0, stream>>>(x, res, out + OUT_QT_OFF);
    vq_scalars<<<1, 256, 0, stream>>>(used, loss, out);
}

// Round 11
// 337.219 us; speedup vs baseline: 6.0786x; 1.7707x over previous
//
#include <hip/hip_runtime.h>
#include <hip/hip_bf16.h>
#include <math.h>

// Problem constants
#define Bn   16
#define Dn   64
#define Tn   3000
#define Nn   (Bn*Tn)          // 48000
#define NCB  8
#define Kn   1024
#define KTB  64               // codes per k-chunk (LDS staged)
#define NCHK (Kn/KTB)         // 16 chunks per codebook
#define NTB  64               // n per block
#define NBLK (Nn/NTB)         // 750 (exact) <= 768 = 256CU x 3 blocks
#define EPSF 8e-3f            // candidate band (3-pass split err ~5e-5; huge margin)
#define QMAX 512              // per-stage queue capacity (typ ~150-250 used)

// LDS layout (bytes), total 52496 -> 3 blocks/CU (54613 cap)
#define SM_RH   0                      // bf16 [64n][64d] swizzled = 8192
#define SM_RL   8192                   // 8192
#define SM_EH   16384                  // bf16 [64k][64d] swizzled = 8192
#define SM_EL   24576                  // 8192
#define SM_RF   32768                  // float [64d][64n] = 16384 (exact residual)
#define SM_SE   49152                  // float[64] chunk selds = 256
#define SM_SR   49408                  // float[64] = 256
#define SM_BEST 49664                  // u64[64] = 512
#define SM_QCNT 50176                  // int (+pad) = 16
#define SM_QUE  50192                  // u32[QMAX] = 2048
#define SM_BK   52240                  // int[64] = 256
#define SM_TOT  52496
// aliases on SM_QUE (queue dead at those times): srpart[256]f, red[256]f

// Workspace byte offsets (layout kept from R10; WS_RES now unused)
#define WS_RES  0
#define WS_EHI  12288000                       // u8[8cb][16chk][8192] pre-swizzled bf16 hi
#define WS_ELO  13336576                       // same, lo
#define WS_SE   14385152                       // float[NCB*Kn]
#define WS_USED 14417920                       // float[NCB*Kn]
#define WS_LOSS 14450688                       // float[1] (+pad)

// Output element offsets (fp32 elements)
#define OUT_QT_OFF  0
#define OUT_IDX_OFF 3072000
#define OUT_SC_OFF  3456000

typedef __attribute__((ext_vector_type(4))) float f32x4;
typedef __attribute__((ext_vector_type(8))) short s16x8;

__device__ __forceinline__ unsigned short f2bf(float x) {   // RNE bf16 bits
    unsigned int u = __float_as_uint(x);
    unsigned int r = (u + 0x7FFFu + ((u >> 16) & 1u)) >> 16;
    return (unsigned short)r;
}
__device__ __forceinline__ float bf2f(unsigned short h) {
    return __uint_as_float(((unsigned int)h) << 16);
}

// ---------- precompute ||e_k||^2 for all 8 codebooks ----------
__global__ void vq_se(const float* __restrict__ emb, float* __restrict__ se)
{
    int r = blockIdx.x * 256 + threadIdx.x;   // 0..8191
    if (r < NCB*Kn) {
        const float* p = emb + r*Dn;
        float a0=0.f, a1=0.f, a2=0.f, a3=0.f;
        #pragma unroll
        for (int d = 0; d < Dn; d += 4) {
            a0 = fmaf(p[d+0], p[d+0], a0);
            a1 = fmaf(p[d+1], p[d+1], a1);
            a2 = fmaf(p[d+2], p[d+2], a2);
            a3 = fmaf(p[d+3], p[d+3], a3);
        }
        se[r] = (a0+a1)+(a2+a3);
    }
}

// ---------- precompute bf16 hi/lo split of all codebooks, pre-swizzled ----------
__global__ void vq_ebf(const float* __restrict__ emb, char* __restrict__ ehi,
                       char* __restrict__ elo)
{
    int idx = blockIdx.x * 256 + threadIdx.x;   // < 65536
    int r = idx >> 3;                            // cb*1024 + k
    int s = idx & 7;                             // dim slice
    const float* p = emb + (size_t)r*Dn + s*8;
    s16x8 hh, ll;
    #pragma unroll
    for (int j = 0; j < 8; ++j) {
        float v = p[j];
        unsigned short h = f2bf(v);
        hh[j] = (short)h;
        ll[j] = (short)f2bf(v - bf2f(h));
    }
    int cb = r >> 10, kk = r & 1023, c = kk >> 6, kl = kk & 63;
    size_t off = (size_t)cb*131072 + (size_t)c*8192 + kl*128 + ((s ^ (kl & 7)) << 4);
    *(s16x8*)(ehi + off) = hh;
    *(s16x8*)(elo + off) = ll;
}

// exact fp32 rescore: d2 = (sr - 2*dot) + sek  (identical chain since R8, verified)
__device__ __forceinline__
float vq_rescore(const float* rf, float sr, float sek,
                 const float* __restrict__ emb_cb, int n, int kg)
{
    const float4* ep = (const float4*)(emb_cb + (size_t)kg*Dn);
    float q0=0.f,q1=0.f,q2=0.f,q3=0.f;
    #pragma unroll 4
    for (int m = 0; m < 16; ++m) {
        float4 e4 = ep[m];
        q0 = fmaf(rf[(4*m+0)*64 + n], e4.x, q0);
        q1 = fmaf(rf[(4*m+1)*64 + n], e4.y, q1);
        q2 = fmaf(rf[(4*m+2)*64 + n], e4.z, q2);
        q3 = fmaf(rf[(4*m+3)*64 + n], e4.w, q3);
    }
    float dot = (q0+q1)+(q2+q3);
    return (sr - 2.0f*dot) + sek;
}

// ---------- mega kernel: all 8 stages fused, residual lives in LDS ----------
// grid NBLK, block 256 (4 waves). Wave w owns n-rows [w*16, w*16+16).
__global__ __launch_bounds__(256, 3)
void vq_mega(const float* __restrict__ x, const float* __restrict__ emb,
             const char* __restrict__ ehib, const char* __restrict__ elob,
             const float* __restrict__ se_g,
             float* __restrict__ out_qt, float* __restrict__ out_idx,
             float* __restrict__ used_g, float* __restrict__ loss_acc)
{
    __shared__ __align__(16) char smem[SM_TOT];
    float*  rf     = (float*)(smem + SM_RF);
    float*  selds  = (float*)(smem + SM_SE);
    float*  lds_sr = (float*)(smem + SM_SR);
    unsigned long long* best64 = (unsigned long long*)(smem + SM_BEST);
    int*    qcnt   = (int*)(smem + SM_QCNT);
    unsigned int* que = (unsigned int*)(smem + SM_QUE);
    float*  srpart = (float*)(smem + SM_QUE);    // alias (stage transitions only)
    int*    bkL    = (int*)(smem + SM_BK);

    const int tid = threadIdx.x;
    const int n0 = blockIdx.x * NTB;
    const int lane = tid & 63, w = tid >> 6;
    const int lrow = lane & 15, lhi = lane >> 4;
    const int nl = tid & 63;
    const int dg = tid >> 6;
    const float4* hsrc = (const float4*)ehib;
    const float4* lsrc = (const float4*)elob;

    // ---- prologue: stage R from x (fp32 rf + bf16 hi/lo swizzled) + sr partials ----
    {
        const int n = n0 + nl;
        const int b = n / Tn, t = n % Tn;
        const float* gp = x + b*(Dn*Tn) + t;
        float v[16];
        #pragma unroll
        for (int j = 0; j < 16; ++j) v[j] = gp[(dg*16 + j)*Tn];
        float a0=0.f,a1=0.f,a2=0.f,a3=0.f;
        #pragma unroll
        for (int j = 0; j < 16; j += 4) {
            a0 = fmaf(v[j+0], v[j+0], a0);
            a1 = fmaf(v[j+1], v[j+1], a1);
            a2 = fmaf(v[j+2], v[j+2], a2);
            a3 = fmaf(v[j+3], v[j+3], a3);
        }
        srpart[dg*64 + nl] = (a0+a1)+(a2+a3);
        unsigned short hi[16], lo[16];
        #pragma unroll
        for (int j = 0; j < 16; ++j) {
            rf[(dg*16 + j)*64 + nl] = v[j];
            hi[j] = f2bf(v[j]);
            lo[j] = f2bf(v[j] - bf2f(hi[j]));
        }
        s16x8 ph0, ph1, pl0, pl1;
        #pragma unroll
        for (int j = 0; j < 8; ++j) {
            ph0[j] = (short)hi[j];   ph1[j] = (short)hi[j+8];
            pl0[j] = (short)lo[j];   pl1[j] = (short)lo[j+8];
        }
        const int s0 = dg*2, s1 = dg*2 + 1, nx = nl & 7;
        *(s16x8*)(smem + SM_RH + nl*128 + ((s0 ^ nx) << 4)) = ph0;
        *(s16x8*)(smem + SM_RH + nl*128 + ((s1 ^ nx) << 4)) = ph1;
        *(s16x8*)(smem + SM_RL + nl*128 + ((s0 ^ nx) << 4)) = pl0;
        *(s16x8*)(smem + SM_RL + nl*128 + ((s1 ^ nx) << 4)) = pl1;
    }
    if (tid < 64) best64[tid] = ~0ULL;
    if (tid == 0) qcnt[0] = 0;
    __syncthreads();                               // srpart ready
    if (tid < 64)
        lds_sr[tid] = (srpart[tid] + srpart[64+tid]) + (srpart[128+tid] + srpart[192+tid]);
    // stage E(cb0, chunk0) directly
    ((float4*)(smem + SM_EH))[tid]      = hsrc[tid];
    ((float4*)(smem + SM_EH))[tid+256]  = hsrc[tid+256];
    ((float4*)(smem + SM_EL))[tid]      = lsrc[tid];
    ((float4*)(smem + SM_EL))[tid+256]  = lsrc[tid+256];
    if (tid < 64) selds[tid] = se_g[tid];

    float lsum = 0.f;

    // ================= stage loop =================
    for (int s = 0; s < NCB; ++s) {
        const float* emb_s = emb + (size_t)s*(Kn*Dn);
        float m_run = INFINITY;

        // ---- chunk loop ----
        for (int c = 0; c < NCHK; ++c) {
            __syncthreads();                       // E(c)/selds(c)/RH/RL ready
            // prefetch next E chunk (or next codebook's chunk 0) into regs
            const bool pre = (c < NCHK-1) || (s < NCB-1);
            float4 h0, h1, l0, l1; float sepre = 0.f;
            if (pre) {
                size_t nb = (c < NCHK-1) ? ((size_t)s*8192 + (size_t)(c+1)*512)
                                         : ((size_t)(s+1)*8192);
                h0 = hsrc[nb + tid]; h1 = hsrc[nb + 256 + tid];
                l0 = lsrc[nb + tid]; l1 = lsrc[nb + 256 + tid];
                if (tid < 64)
                    sepre = se_g[(c < NCHK-1) ? (s*Kn + (c+1)*KTB + tid)
                                              : ((s+1)*Kn + tid)];
            }

            // MFMA: acc[i] = S[k = i*16 + ..][n = w*16 + ..]  (3-pass split)
            f32x4 acc[4] = {};
            #pragma unroll
            for (int ks = 0; ks < 2; ++ks) {
                const int sdim = ks*4 + lhi;
                const int swz = ((sdim ^ (lrow & 7)) << 4);
                const size_t roff = (size_t)(w*16 + lrow)*128 + swz;
                const size_t eoff = (size_t)lrow*128 + swz;
                s16x8 bh = *(const s16x8*)(smem + SM_RH + roff);
                s16x8 bl = *(const s16x8*)(smem + SM_RL + roff);
                #pragma unroll
                for (int i = 0; i < 4; ++i) {
                    s16x8 ah = *(const s16x8*)(smem + SM_EH + eoff + i*2048);
                    s16x8 al = *(const s16x8*)(smem + SM_EL + eoff + i*2048);
                    acc[i] = __builtin_amdgcn_mfma_f32_16x16x32_bf16(ah, bh, acc[i], 0, 0, 0);
                    acc[i] = __builtin_amdgcn_mfma_f32_16x16x32_bf16(ah, bl, acc[i], 0, 0, 0);
                    acc[i] = __builtin_amdgcn_mfma_f32_16x16x32_bf16(al, bh, acc[i], 0, 0, 0);
                }
            }

            // wave-local approx min over this chunk's 64 codes for my n
            float cv[4][4];
            float m = INFINITY;
            #pragma unroll
            for (int i = 0; i < 4; ++i)
                #pragma unroll
                for (int rg = 0; rg < 4; ++rg) {
                    float c2 = selds[i*16 + lhi*4 + rg] - 2.0f*acc[i][rg];
                    cv[i][rg] = c2;
                    m = fminf(m, c2);
                }
            m = fminf(m, __shfl_xor(m, 16, 64));
            m = fminf(m, __shfl_xor(m, 32, 64));
            const float thr = fminf(m_run, m) + EPSF;
            m_run = fminf(m_run, m);
            const int nlocal = w*16 + lrow;

            // push candidates (queue consumed once per stage)
            #pragma unroll
            for (int i = 0; i < 4; ++i)
                #pragma unroll
                for (int rg = 0; rg < 4; ++rg) {
                    if (cv[i][rg] <= thr) {
                        int kl = i*16 + lhi*4 + rg;
                        int kg = c*KTB + kl;
                        int slot = atomicAdd(qcnt, 1);
                        if (slot < QMAX) {
                            que[slot] = ((unsigned)nlocal << 10) | (unsigned)kg;
                        } else {   // overflow fallback (rare)
                            float d2e = vq_rescore(rf, lds_sr[nlocal], selds[kl],
                                                   emb_s, nlocal, kg);
                            unsigned long long pk =
                                ((unsigned long long)__float_as_uint(d2e) << 32) | (unsigned)kg;
                            atomicMin(&best64[nlocal], pk);
                        }
                    }
                }
            __syncthreads();                       // E(c) consumed; pushes visible
            if (pre) {
                ((float4*)(smem + SM_EH))[tid]     = h0;
                ((float4*)(smem + SM_EH))[tid+256] = h1;
                ((float4*)(smem + SM_EL))[tid]     = l0;
                ((float4*)(smem + SM_EL))[tid+256] = l1;
                if (tid < 64) selds[tid] = sepre;
            }
        }

        // ---- per-stage parallel rescore of queued candidates ----
        const int cnt = min(qcnt[0], QMAX);
        for (int e = tid; e < cnt; e += 256) {
            unsigned ent = que[e];
            int nn = (int)(ent >> 10);
            int kg = (int)(ent & 1023);
            float sek = se_g[s*Kn + kg];
            float d2e = vq_rescore(rf, lds_sr[nn], sek, emb_s, nn, kg);
            unsigned long long pk =
                ((unsigned long long)__float_as_uint(d2e) << 32) | (unsigned)kg;
            atomicMin(&best64[nn], pk);
        }
        __syncthreads();                           // best64 final; queue dead

        // ---- finalize stage: idx/used; residual update ----
        if (tid < 64) {
            int bk = (int)(best64[tid] & 0xFFFFFFFFull) & (Kn - 1);
            bkL[tid] = bk;
            out_idx[s*Nn + n0 + tid] = (float)bk;
            used_g[s*Kn + bk] = 1.0f;
            best64[tid] = ~0ULL;                   // reset for next stage
        }
        if (tid == 0) qcnt[0] = 0;
        __syncthreads();                           // bkL visible

        const float* ep = emb_s + (size_t)bkL[nl]*Dn;
        if (s < NCB-1) {
            float nv[16];
            #pragma unroll
            for (int j = 0; j < 16; ++j) {
                int d = dg*16 + j;
                float rv = rf[d*64 + nl];
                float q  = ep[d];
                float diff = rv - q;               // loss uses raw q
                lsum = fmaf(diff, diff, lsum);
                float qst = rv + (q - rv);         // straight-through, fp32-faithful
                nv[j] = rv - qst;
                rf[d*64 + nl] = nv[j];
            }
            // sr partials of new residual
            float a0=0.f,a1=0.f,a2=0.f,a3=0.f;
            #pragma unroll
            for (int j = 0; j < 16; j += 4) {
                a0 = fmaf(nv[j+0], nv[j+0], a0);
                a1 = fmaf(nv[j+1], nv[j+1], a1);
                a2 = fmaf(nv[j+2], nv[j+2], a2);
                a3 = fmaf(nv[j+3], nv[j+3], a3);
            }
            srpart[dg*64 + nl] = (a0+a1)+(a2+a3);
            // bf16 split of new residual -> RH/RL
            unsigned short hi[16], lo[16];
            #pragma unroll
            for (int j = 0; j < 16; ++j) {
                hi[j] = f2bf(nv[j]);
                lo[j] = f2bf(nv[j] - bf2f(hi[j]));
            }
            s16x8 ph0, ph1, pl0, pl1;
            #pragma unroll
            for (int j = 0; j < 8; ++j) {
                ph0[j] = (short)hi[j];   ph1[j] = (short)hi[j+8];
                pl0[j] = (short)lo[j];   pl1[j] = (short)lo[j+8];
            }
            const int s0 = dg*2, s1 = dg*2 + 1, nx = nl & 7;
            *(s16x8*)(smem + SM_RH + nl*128 + ((s0 ^ nx) << 4)) = ph0;
            *(s16x8*)(smem + SM_RH + nl*128 + ((s1 ^ nx) << 4)) = ph1;
            *(s16x8*)(smem + SM_RL + nl*128 + ((s0 ^ nx) << 4)) = pl0;
            *(s16x8*)(smem + SM_RL + nl*128 + ((s1 ^ nx) << 4)) = pl1;
            __syncthreads();                       // srpart ready
            if (tid < 64)
                lds_sr[tid] = (srpart[tid] + srpart[64+tid])
                            + (srpart[128+tid] + srpart[192+tid]);
            // next stage's chunk-0 top barrier covers lds_sr/RH/RL visibility
        } else {
            // final stage: qt = x - res_final, written directly
            const int n = n0 + nl;
            const int b = n / Tn, t = n % Tn;
            const float* xp = x + b*(Dn*Tn) + t;
            float* qp = out_qt + b*(Dn*Tn) + t;
            #pragma unroll
            for (int j = 0; j < 16; ++j) {
                int d = dg*16 + j;
                float rv = rf[d*64 + nl];
                float q  = ep[d];
                float diff = rv - q;
                lsum = fmaf(diff, diff, lsum);
                float qst = rv + (q - rv);
                float rn = rv - qst;
                qp[d*Tn] = xp[d*Tn] - rn;
            }
        }
    }

    // ---- loss reduce (once for all 8 stages) ----
    float* red = (float*)(smem + SM_QUE);          // queue dead
    red[tid] = lsum;
    __syncthreads();
    for (int s2 = 128; s2 > 0; s2 >>= 1) {
        if (tid < s2) red[tid] += red[tid + s2];
        __syncthreads();
    }
    if (tid == 0) atomicAdd(loss_acc, red[0]);
}

// ---------- scalars: (commit+codebook)/NCB and utilization (fp32 out) ----------
__global__ void vq_scalars(const float* __restrict__ used, const float* __restrict__ loss_acc,
                           float* __restrict__ out)
{
    __shared__ float red[256];
    float s = 0.f;
    for (int j = threadIdx.x; j < NCB*Kn; j += 256) s += used[j];
    red[threadIdx.x] = s;
    __syncthreads();
    for (int st = 128; st > 0; st >>= 1) {
        if (threadIdx.x < st) red[threadIdx.x] += red[threadIdx.x + st];
        __syncthreads();
    }
    if (threadIdx.x == 0) {
        float sumsq = loss_acc[0];
        float total_loss = 2.0f * sumsq / (float)(Nn*Dn);  // sum over stages of commit+codebook
        out[OUT_SC_OFF + 0] = total_loss / (float)NCB;
        out[OUT_SC_OFF + 1] = red[0] / (float)(NCB*Kn);
    }
}

extern "C" void kernel_launch(void* const* d_in, const int* in_sizes, int n_in,
                              void* d_out, int out_size, void* d_ws, size_t ws_size,
                              hipStream_t stream)
{
    const float* x      = (const float*)d_in[0];
    const float* embeds = (const float*)d_in[1];
    float* out = (float*)d_out;
    char* ws = (char*)d_ws;

    char*  ehi  = ws + WS_EHI;
    char*  elo  = ws + WS_ELO;
    float* se   = (float*)(ws + WS_SE);
    float* used = (float*)(ws + WS_USED);
    float* loss = (float*)(ws + WS_LOSS);

    hipMemsetAsync(used, 0, (size_t)NCB*Kn*sizeof(float) + 16, stream);

    vq_se<<<(NCB*Kn + 255)/256, 256, 0, stream>>>(embeds, se);
    vq_ebf<<<256, 256, 0, stream>>>(embeds, ehi, elo);

    vq_mega<<<NBLK, 256, 0, stream>>>(x, embeds, ehi, elo, se,
                                      out + OUT_QT_OFF, out + OUT_IDX_OFF,
                                      used, loss);

    vq_scalars<<<1, 256, 0, stream>>>(used, loss, out);
}